// Round 3
// baseline (12249.902 us; speedup 1.0000x reference)
//
#include <hip/hip_runtime.h>
#include <hip/hip_bf16.h>

#define BB   256   // batch
#define TT   512   // time steps
#define XSZ  256   // input size
#define HSZ  256   // hidden size
#define GSZ  1024  // 4*HSZ gate cols
#define KK   512   // folded K = HSZ (k 0..255) + XSZ (k 256..511)
#define GLDSW 1028 // gate LDS row stride (dwords)

typedef __bf16 bf16_t;
typedef __attribute__((ext_vector_type(8))) __bf16 bf16x8;
typedef __attribute__((ext_vector_type(4))) float  f32x4;

__device__ __forceinline__ float sigmoidf_(float v) { return 1.0f / (1.0f + __expf(-v)); }
__device__ __forceinline__ float tanhf_(float v)    { return 1.0f - 2.0f / (1.0f + __expf(2.0f * v)); }
__device__ __forceinline__ f32x4 splat4(float v)    { f32x4 r = {v, v, v, v}; return r; }

// ---------------- prep: bias[g*256+c] = bx_g[c] + bh_g[c] ----------------
__global__ void prep_bias(const float* bx0, const float* bh0, const float* bx1, const float* bh1,
                          const float* bx2, const float* bh2, const float* bx3, const float* bh3,
                          float* bias) {
  const float* bxs[4] = {bx0, bx1, bx2, bx3};
  const float* bhs[4] = {bh0, bh1, bh2, bh3};
  int g = blockIdx.x, c = threadIdx.x;
  bias[g * 256 + c] = bxs[g][c] + bhs[g][c];
}

// ---------------- prep: fragment-linear weight pack ----------------
// Wtf = 64 n-tiles x 16 kt chunks of 1024 B. Within a chunk, byte layout is
// exactly the MFMA B-fragment order: lane (l4*16+l15) reads 16 B at lane*16,
// holding col (ntile*16+l15), k = kt*32 + l4*8 .. +7.  k<256 -> Wh, else Wx.
__global__ void prep_wtf(const float* wx0, const float* wh0, const float* wx1, const float* wh1,
                         const float* wx2, const float* wh2, const float* wx3, const float* wh3,
                         bf16_t* Wtf) {
  const float* whs[4] = {wh0, wh1, wh2, wh3};
  const float* wxs[4] = {wx0, wx1, wx2, wx3};
  int id   = blockIdx.x * 256 + threadIdx.x;   // 65536 chunks of 16 B
  int c15  = id & 15;
  int l4c  = (id >> 4) & 3;
  int kt   = (id >> 6) & 15;
  int ng   = id >> 10;                         // 0..63
  int C    = ng * 16 + c15;                    // global gate col
  int g    = C >> 8, c = C & 255;
  int k0   = kt * 32 + l4c * 8;
  const float* src = (k0 < 256) ? (whs[g] + (size_t)k0 * 256 + c)
                                : (wxs[g] + (size_t)(k0 - 256) * 256 + c);
  bf16x8 v;
#pragma unroll
  for (int i = 0; i < 8; ++i) v[i] = (__bf16)src[(size_t)i * 256];
  reinterpret_cast<bf16x8*>(Wtf)[id] = v;
}

// ---------------- prep: x f32 -> bf16 ----------------
__global__ void prep_xbf(const float* __restrict__ x, bf16_t* __restrict__ xb) {
  size_t id = (size_t)blockIdx.x * 256 + threadIdx.x;   // x8 elements
  const float* p = x + id * 8;
  f32x4 lo = *reinterpret_cast<const f32x4*>(p);
  f32x4 hi = *reinterpret_cast<const f32x4*>(p + 4);
  bf16x8 v;
#pragma unroll
  for (int i = 0; i < 4; ++i) { v[i] = (__bf16)lo[i]; v[i + 4] = (__bf16)hi[i]; }
  reinterpret_cast<bf16x8*>(xb)[id] = v;
}

// ---------------- main sequential LSTM kernel ----------------
// 16 independent blocks; block owns batch rows b0..b0+15 for ALL 512 steps.
// No grid sync. h lives in LDS (fragment-linear). Weights stream from L2.
template <bool XBF>
__global__ __launch_bounds__(512, 2)
void lstm_seq(const void* __restrict__ xsrc, const bf16_t* __restrict__ Wtf,
              const float* __restrict__ bias, float* __restrict__ out)
{
  __shared__ __align__(16) float  glds[16 * GLDSW];   // gate tile 16 x 1024 (+pad)
  __shared__ __align__(16) char   hlds[8192];         // h, fragment-linear: 8 kt x 1 KB

  const int tid  = threadIdx.x;
  const int w    = tid >> 6;
  const int lane = tid & 63;
  const int l15  = lane & 15, l4 = lane >> 4;
  const int b0   = blockIdx.x * 16;

  const float*  xf32 = (const float*)xsrc;
  const bf16_t* xbf  = (const bf16_t*)xsrc;

  // bias per n-tile (col = w*128 + n*16 + l15)
  float bias_v[8];
#pragma unroll
  for (int n = 0; n < 8; ++n) bias_v[n] = bias[w * 128 + n * 16 + l15];

  // per-thread cell ownership: row = tid>>5 (0..15), cols cj..cj+7
  const int crow = tid >> 5;
  const int cj   = (tid & 31) * 8;
  float cst[8];
#pragma unroll
  for (int i = 0; i < 8; ++i) cst[i] = 0.f;
  // h LDS write slot for this thread's 8 cols (single 16B chunk)
  char* hw = hlds + (cj >> 5) * 1024 + ((cj >> 3) & 3) * 256 + crow * 16;

  // zero h (t=0: h=0 contribution)
  reinterpret_cast<bf16x8*>(hlds)[tid & 511] = bf16x8{};

  // B-chunk base for this wave/lane: chunk(n,kt) at Wtf + ((w*8+n)*16+kt)*1024 + lane*16
  const char* Bp = (const char*)Wtf + ((size_t)w * 8 * 16) * 1024 + lane * 16;

  // ---- prologue: x A-frags for t=0, B kt=0
  bf16x8 ax[8];
#pragma unroll
  for (int k8 = 0; k8 < 8; ++k8) {
    if constexpr (XBF) {
      ax[k8] = *reinterpret_cast<const bf16x8*>(
          xbf + (size_t)(b0 + l15) * (TT * XSZ) + k8 * 32 + l4 * 8);
    } else {
      const float* xp = xf32 + (size_t)(b0 + l15) * (TT * XSZ) + k8 * 32 + l4 * 8;
      f32x4 lo = *reinterpret_cast<const f32x4*>(xp);
      f32x4 hi = *reinterpret_cast<const f32x4*>(xp + 4);
#pragma unroll
      for (int i = 0; i < 4; ++i) { ax[k8][i] = (__bf16)lo[i]; ax[k8][i + 4] = (__bf16)hi[i]; }
    }
  }
  bf16x8 Bb[2][8];
#pragma unroll
  for (int n = 0; n < 8; ++n)
    Bb[0][n] = *reinterpret_cast<const bf16x8*>(Bp + (size_t)n * 16384);

  __syncthreads();   // hlds zeroed

#pragma unroll 1
  for (int t = 0; t < TT; ++t) {
    // ---- gates = bias + [h | x_t] @ W   (128 MFMAs/wave, B double-buffered)
    f32x4 acc[8];
#pragma unroll
    for (int n = 0; n < 8; ++n) acc[n] = splat4(bias_v[n]);

#pragma unroll
    for (int kt = 0; kt < 16; ++kt) {
      if (kt < 15) {
#pragma unroll
        for (int n = 0; n < 8; ++n)
          Bb[(kt + 1) & 1][n] =
              *reinterpret_cast<const bf16x8*>(Bp + (size_t)n * 16384 + (kt + 1) * 1024);
      }
      bf16x8 a;
      if (kt < 8) a = *reinterpret_cast<const bf16x8*>(hlds + kt * 1024 + lane * 16);
      else        a = ax[kt - 8];
#pragma unroll
      for (int n = 0; n < 8; ++n)
        acc[n] = __builtin_amdgcn_mfma_f32_16x16x32_bf16(a, Bb[kt & 1][n], acc[n], 0, 0, 0);
    }

    // ---- gates -> LDS (C-frag: row = l4*4+r, col = w*128 + n*16 + l15)
#pragma unroll
    for (int n = 0; n < 8; ++n) {
      const int col = w * 128 + n * 16 + l15;
#pragma unroll
      for (int r = 0; r < 4; ++r)
        glds[(l4 * 4 + r) * GLDSW + col] = acc[n][r];
    }

    // ---- off critical path: prefetch x A-frags for t+1 and B kt=0
    if (t + 1 < TT) {
#pragma unroll
      for (int k8 = 0; k8 < 8; ++k8) {
        if constexpr (XBF) {
          ax[k8] = *reinterpret_cast<const bf16x8*>(
              xbf + (size_t)(b0 + l15) * (TT * XSZ) + (size_t)(t + 1) * XSZ + k8 * 32 + l4 * 8);
        } else {
          const float* xp = xf32 + (size_t)(b0 + l15) * (TT * XSZ) + (size_t)(t + 1) * XSZ + k8 * 32 + l4 * 8;
          f32x4 lo = *reinterpret_cast<const f32x4*>(xp);
          f32x4 hi = *reinterpret_cast<const f32x4*>(xp + 4);
#pragma unroll
          for (int i = 0; i < 4; ++i) { ax[k8][i] = (__bf16)lo[i]; ax[k8][i + 4] = (__bf16)hi[i]; }
        }
      }
    }
#pragma unroll
    for (int n = 0; n < 8; ++n)
      Bb[0][n] = *reinterpret_cast<const bf16x8*>(Bp + (size_t)n * 16384);

    __syncthreads();

    // ---- combine: thread owns (crow, cj..cj+7)
    const float* gp = &glds[crow * GLDSW + cj];
    f32x4 iv0 = *reinterpret_cast<const f32x4*>(gp);
    f32x4 iv1 = *reinterpret_cast<const f32x4*>(gp + 4);
    f32x4 fv0 = *reinterpret_cast<const f32x4*>(gp + 256);
    f32x4 fv1 = *reinterpret_cast<const f32x4*>(gp + 260);
    f32x4 gv0 = *reinterpret_cast<const f32x4*>(gp + 512);
    f32x4 gv1 = *reinterpret_cast<const f32x4*>(gp + 516);
    f32x4 ov0 = *reinterpret_cast<const f32x4*>(gp + 768);
    f32x4 ov1 = *reinterpret_cast<const f32x4*>(gp + 772);

    float hval[8];
#pragma unroll
    for (int k = 0; k < 8; ++k) {
      float ig = (k < 4) ? iv0[k & 3] : iv1[k & 3];
      float fg = (k < 4) ? fv0[k & 3] : fv1[k & 3];
      float gg = (k < 4) ? gv0[k & 3] : gv1[k & 3];
      float og = (k < 4) ? ov0[k & 3] : ov1[k & 3];
      float i_t = sigmoidf_(ig);
      float f_t = sigmoidf_(fg);
      float g_t = tanhf_(gg);
      float o_t = sigmoidf_(og);
      float cn  = f_t * cst[k] + i_t * g_t;
      cst[k]  = cn;
      hval[k] = o_t * tanhf_(cn);
    }

    if (t + 1 < TT) {
      bf16x8 h8;
#pragma unroll
      for (int k = 0; k < 8; ++k) h8[k] = (__bf16)hval[k];
      *reinterpret_cast<bf16x8*>(hw) = h8;
    } else {
      float* op = out + (size_t)(b0 + crow) * HSZ + cj;
      f32x4 h0 = {hval[0], hval[1], hval[2], hval[3]};
      f32x4 h1 = {hval[4], hval[5], hval[6], hval[7]};
      f32x4 c0 = {cst[0], cst[1], cst[2], cst[3]};
      f32x4 c1 = {cst[4], cst[5], cst[6], cst[7]};
      *reinterpret_cast<f32x4*>(op)     = h0;
      *reinterpret_cast<f32x4*>(op + 4) = h1;
      *reinterpret_cast<f32x4*>(op + (size_t)BB * HSZ)     = c0;
      *reinterpret_cast<f32x4*>(op + (size_t)BB * HSZ + 4) = c1;
    }

    __syncthreads();   // h(t+1) visible in LDS; glds safe to overwrite
  }
}

extern "C" void kernel_launch(void* const* d_in, const int* in_sizes, int n_in,
                              void* d_out, int out_size, void* d_ws, size_t ws_size,
                              hipStream_t stream) {
  const float* x = (const float*)d_in[0];
  const float *wx[4], *wh[4], *bx[4], *bh[4];
  for (int g = 0; g < 4; ++g) {          // dict order: wx, wh, bx, bh per gate (i,f,g,o)
    wx[g] = (const float*)d_in[1 + 4 * g];
    wh[g] = (const float*)d_in[2 + 4 * g];
    bx[g] = (const float*)d_in[3 + 4 * g];
    bh[g] = (const float*)d_in[4 + 4 * g];
  }

  char* ws = (char*)d_ws;
  float*  bias = (float*)ws;                               // 4 KB
  bf16_t* Wtf  = (bf16_t*)(ws + 4096);                     // 1 MB
  bf16_t* xbf  = (bf16_t*)(ws + 4096 + 1048576);           // 64 MB (optional)
  const size_t need_xbf = 4096 + 1048576 + (size_t)BB * TT * XSZ * 2;

  prep_bias<<<dim3(4), dim3(256), 0, stream>>>(bx[0], bh[0], bx[1], bh[1],
                                               bx[2], bh[2], bx[3], bh[3], bias);
  prep_wtf<<<dim3(256), dim3(256), 0, stream>>>(wx[0], wh[0], wx[1], wh[1],
                                                wx[2], wh[2], wx[3], wh[3], Wtf);
  if (ws_size >= need_xbf) {
    prep_xbf<<<dim3((BB * TT * XSZ / 8) / 256), dim3(256), 0, stream>>>(x, xbf);
    lstm_seq<true><<<dim3(16), dim3(512), 0, stream>>>(xbf, Wtf, bias, (float*)d_out);
  } else {
    lstm_seq<false><<<dim3(16), dim3(512), 0, stream>>>(x, Wtf, bias, (float*)d_out);
  }
}

// Round 4
// 2179.021 us; speedup vs baseline: 5.6217x; 5.6217x over previous
//
#include <hip/hip_runtime.h>
#include <hip/hip_bf16.h>

#define BB   256   // batch
#define TT   512   // time steps
#define XSZ  256   // input size
#define HSZ  256   // hidden size
#define GLDSW 132  // gate LDS row stride (f32), 16 rows

typedef __bf16 bf16_t;
typedef __attribute__((ext_vector_type(8))) __bf16 bf16x8;
typedef __attribute__((ext_vector_type(4))) float  f32x4;

__device__ __forceinline__ float sigmoidf_(float v) { return 1.0f / (1.0f + __expf(-v)); }
__device__ __forceinline__ float tanhf_(float v)    { return 1.0f - 2.0f / (1.0f + __expf(2.0f * v)); }

// ---------------- prep: bias[g*256+c] = bx_g[c] + bh_g[c] ----------------
__global__ void prep_bias(const float* bx0, const float* bh0, const float* bx1, const float* bh1,
                          const float* bx2, const float* bh2, const float* bx3, const float* bh3,
                          float* bias) {
  const float* bxs[4] = {bx0, bx1, bx2, bx3};
  const float* bhs[4] = {bh0, bh1, bh2, bh3};
  int g = blockIdx.x, c = threadIdx.x;
  bias[g * 256 + c] = bxs[g][c] + bhs[g][c];
}

// ---------------- prep: fragment-linear weight pack ----------------
// Chunk cid = (j*8 + w)*16 + kt  (j=col-block 0..7, w=wave 0..7, kt=0..15).
// Within chunk, lane L holds 16 B: col C = sec*256 + j*32 + half*16 + (L&15)
// (sec=w>>1, half=w&1), k = kt*32 + (L>>4)*8 .. +7.  k<256 -> Wh, else Wx.
__global__ void prep_wtf(const float* wx0, const float* wh0, const float* wx1, const float* wh1,
                         const float* wx2, const float* wh2, const float* wx3, const float* wh3,
                         bf16_t* Wtf) {
  const float* whs[4] = {wh0, wh1, wh2, wh3};
  const float* wxs[4] = {wx0, wx1, wx2, wx3};
  int id = blockIdx.x * 256 + threadIdx.x;    // 65536 = 1024 chunks x 64 lanes
  int L  = id & 63;
  int kt = (id >> 6) & 15;
  int w  = (id >> 10) & 7;
  int j  = (id >> 13) & 7;
  int sec = w >> 1, half = w & 1;
  int c   = j * 32 + half * 16 + (L & 15);    // hidden col 0..255
  int k0  = kt * 32 + (L >> 4) * 8;
  const float* src = (k0 < 256) ? (whs[sec] + (size_t)k0 * 256 + c)
                                : (wxs[sec] + (size_t)(k0 - 256) * 256 + c);
  bf16x8 v;
#pragma unroll
  for (int i = 0; i < 8; ++i) v[i] = (__bf16)src[(size_t)i * 256];
  reinterpret_cast<bf16x8*>(Wtf)[id] = v;
}

// ---------------- prep: x f32 -> bf16 ----------------
__global__ void prep_xbf(const float* __restrict__ x, bf16_t* __restrict__ xb) {
  size_t id = (size_t)blockIdx.x * 256 + threadIdx.x;   // x8 elements
  const float* p = x + id * 8;
  f32x4 lo = *reinterpret_cast<const f32x4*>(p);
  f32x4 hi = *reinterpret_cast<const f32x4*>(p + 4);
  bf16x8 v;
#pragma unroll
  for (int i = 0; i < 4; ++i) { v[i] = (__bf16)lo[i]; v[i + 4] = (__bf16)hi[i]; }
  reinterpret_cast<bf16x8*>(xb)[id] = v;
}

// ---------------- main sequential LSTM ----------------
// 128 blocks = 16 groups (16 batch rows each) x 8 column-blocks (32 hidden cols
// x 4 gates = 128 gate cols). 8 waves/block, one 16x16 n-tile per wave.
// Wh slice in VGPRs (32/lane), Wx slice in LDS. h exchanged via MALL (sc0 sc1),
// deduped through LDS. x-projection for t+1 overlapped after flag publish.
template <bool XBF>
__global__ __launch_bounds__(512, 2)
void lstm_seq(const void* __restrict__ xsrc, const bf16_t* __restrict__ Wtf,
              const float* __restrict__ bias, bf16_t* __restrict__ hbuf0,
              bf16_t* __restrict__ hbuf1, unsigned* __restrict__ flags,
              float* __restrict__ out)
{
  __shared__ __align__(16) char  bxlds[65536];       // Wx slice, fragment-linear
  __shared__ __align__(16) char  hxl[8192];          // h(t) A-frags, 8 kt x 1 KB
  __shared__ __align__(16) float glds[16 * GLDSW];   // gate tile 16 x 128 (+pad)

  const int tid  = threadIdx.x;
  const int w    = tid >> 6;
  const int lane = tid & 63;
  const int l15  = lane & 15, l4 = lane >> 4;
  const int bid  = blockIdx.x;
  const int g    = bid >> 3, j = bid & 7;
  const int b0   = g * 16;
  const int sec  = w >> 1, half = w & 1;
  const int C    = sec * 256 + j * 32 + half * 16 + l15;   // this lane's gate col

  const float*  xf32 = (const float*)xsrc;
  const bf16_t* xbf  = (const bf16_t*)xsrc;

  const float bias_v = bias[C];

  // ---- setup: Bh (kt 0..7) -> VGPRs; Bx (kt 8..15) -> LDS (wave-private)
  const char* wbase = (const char*)Wtf + ((size_t)(j * 8 + w) * 16) * 1024 + lane * 16;
  bf16x8 Bh[8];
#pragma unroll
  for (int kt = 0; kt < 8; ++kt)
    Bh[kt] = *reinterpret_cast<const bf16x8*>(wbase + kt * 1024);
#pragma unroll
  for (int q = 0; q < 8; ++q) {
    bf16x8 v = *reinterpret_cast<const bf16x8*>(wbase + (8 + q) * 1024);
    *reinterpret_cast<bf16x8*>(bxlds + (w * 8 + q) * 1024 + lane * 16) = v;
  }
  __syncthreads();

  // combine ownership: one cell per thread
  const int crow = tid >> 5;          // 0..15 (block row)
  const int ccol = tid & 31;          // 0..31 (hidden col local)
  float cst = 0.f;

  // ---- prologue: acc_x = bias + x_0 @ Wx
  f32x4 acc_x = {bias_v, bias_v, bias_v, bias_v};
  {
#pragma unroll
    for (int k8 = 0; k8 < 8; ++k8) {
      bf16x8 a;
      if constexpr (XBF) {
        a = *reinterpret_cast<const bf16x8*>(
            xbf + (size_t)(b0 + l15) * (TT * XSZ) + k8 * 32 + l4 * 8);
      } else {
        const float* xp = xf32 + (size_t)(b0 + l15) * (TT * XSZ) + k8 * 32 + l4 * 8;
        f32x4 lo = *reinterpret_cast<const f32x4*>(xp);
        f32x4 hi = *reinterpret_cast<const f32x4*>(xp + 4);
#pragma unroll
        for (int i = 0; i < 4; ++i) { a[i] = (__bf16)lo[i]; a[i + 4] = (__bf16)hi[i]; }
      }
      bf16x8 bx = *reinterpret_cast<const bf16x8*>(bxlds + (w * 8 + k8) * 1024 + lane * 16);
      acc_x = __builtin_amdgcn_mfma_f32_16x16x32_bf16(a, bx, acc_x, 0, 0, 0);
    }
  }

#pragma unroll 1
  for (int t = 0; t < TT; ++t) {
    f32x4 acc = acc_x;

    if (t > 0) {
      // ---- poll the 8 producers of our group's h(t)
      const unsigned* fp = flags + (size_t)(g * 8 + (lane & 7)) * 16;
      for (;;) {
        unsigned v;
        asm volatile("global_load_dword %0, %1, off sc0 sc1\n\t"
                     "s_waitcnt vmcnt(0)"
                     : "=v"(v) : "v"(fp) : "memory");
        if (__all((int)(v >= (unsigned)t))) break;
        __builtin_amdgcn_s_sleep(1);
      }
      __builtin_amdgcn_sched_barrier(0);

      // ---- h A-frag: wave w fetches chunk kt=w from MALL, dedupe via LDS
      const bf16_t* hb = (t & 1) ? hbuf1 : hbuf0;   // h(t) lives in buffer t&1
      bf16x8 hch;
      const bf16_t* hp = hb + (size_t)(b0 + l15) * HSZ + w * 32 + l4 * 8;
      asm volatile("global_load_dwordx4 %0, %1, off sc0 sc1\n\t"
                   "s_waitcnt vmcnt(0)"
                   : "=v"(hch) : "v"(hp) : "memory");
      __builtin_amdgcn_sched_barrier(0);
      *reinterpret_cast<bf16x8*>(hxl + w * 1024 + lane * 16) = hch;
      __syncthreads();

      // ---- critical MFMAs: acc += h(t) @ Wh  (B from VGPRs)
#pragma unroll
      for (int kt = 0; kt < 8; ++kt) {
        bf16x8 a = *reinterpret_cast<const bf16x8*>(hxl + kt * 1024 + lane * 16);
        acc = __builtin_amdgcn_mfma_f32_16x16x32_bf16(a, Bh[kt], acc, 0, 0, 0);
      }
    }

    // ---- gates -> LDS (C-frag: row l4*4+r, col_local sec*32 + half*16 + l15)
    {
      const int col = sec * 32 + half * 16 + l15;
#pragma unroll
      for (int r = 0; r < 4; ++r)
        glds[(l4 * 4 + r) * GLDSW + col] = acc[r];
    }
    __syncthreads();

    // ---- combine: thread owns (crow, ccol)
    const float* gp = &glds[crow * GLDSW + ccol];
    float i_t = sigmoidf_(gp[0]);
    float f_t = sigmoidf_(gp[32]);
    float g_t = tanhf_(gp[64]);
    float o_t = sigmoidf_(gp[96]);
    float cn  = f_t * cst + i_t * g_t;
    cst = cn;
    float hval = o_t * tanhf_(cn);

    if (t + 1 < TT) {
      __bf16 hb16 = (__bf16)hval;
      unsigned hv = (unsigned)__builtin_bit_cast(unsigned short, hb16);
      bf16_t* hp = ((t + 1) & 1 ? hbuf1 : hbuf0) + (size_t)(b0 + crow) * HSZ + j * 32 + ccol;
      asm volatile("global_store_short %0, %1, off sc0 sc1" :: "v"(hp), "v"(hv) : "memory");
      asm volatile("s_waitcnt vmcnt(0)" ::: "memory");
      __builtin_amdgcn_sched_barrier(0);
    } else {
      float* op = out + (size_t)(b0 + crow) * HSZ + j * 32 + ccol;
      op[0] = hval;
      op[(size_t)BB * HSZ] = cst;
    }
    __syncthreads();   // all h stores at MALL; glds reusable

    if (t + 1 < TT) {
      if (tid == 0) {
        unsigned fv = (unsigned)(t + 1);
        const unsigned* fp = &flags[(size_t)bid * 16];
        asm volatile("global_store_dword %0, %1, off sc0 sc1" :: "v"(fp), "v"(fv) : "memory");
      }

      // ---- overlapped: acc_x = bias + x_{t+1} @ Wx
      acc_x = f32x4{bias_v, bias_v, bias_v, bias_v};
#pragma unroll
      for (int k8 = 0; k8 < 8; ++k8) {
        bf16x8 a;
        if constexpr (XBF) {
          a = *reinterpret_cast<const bf16x8*>(
              xbf + (size_t)(b0 + l15) * (TT * XSZ) + (size_t)(t + 1) * XSZ + k8 * 32 + l4 * 8);
        } else {
          const float* xp = xf32 + (size_t)(b0 + l15) * (TT * XSZ) + (size_t)(t + 1) * XSZ + k8 * 32 + l4 * 8;
          f32x4 lo = *reinterpret_cast<const f32x4*>(xp);
          f32x4 hi = *reinterpret_cast<const f32x4*>(xp + 4);
#pragma unroll
          for (int i = 0; i < 4; ++i) { a[i] = (__bf16)lo[i]; a[i + 4] = (__bf16)hi[i]; }
        }
        bf16x8 bx = *reinterpret_cast<const bf16x8*>(bxlds + (w * 8 + k8) * 1024 + lane * 16);
        acc_x = __builtin_amdgcn_mfma_f32_16x16x32_bf16(a, bx, acc_x, 0, 0, 0);
      }
    }
  }
}

extern "C" void kernel_launch(void* const* d_in, const int* in_sizes, int n_in,
                              void* d_out, int out_size, void* d_ws, size_t ws_size,
                              hipStream_t stream) {
  const float* x = (const float*)d_in[0];
  const float *wx[4], *wh[4], *bx[4], *bh[4];
  for (int g = 0; g < 4; ++g) {          // dict order: wx, wh, bx, bh per gate (i,f,g,o)
    wx[g] = (const float*)d_in[1 + 4 * g];
    wh[g] = (const float*)d_in[2 + 4 * g];
    bx[g] = (const float*)d_in[3 + 4 * g];
    bh[g] = (const float*)d_in[4 + 4 * g];
  }

  char* ws = (char*)d_ws;
  unsigned* flags = (unsigned*)(ws);                        // 8 KB (128 flags, 64B stride)
  float*    bias  = (float*)(ws + 8192);                    // 4 KB
  bf16_t*   hbuf0 = (bf16_t*)(ws + 16384);                  // 128 KB
  bf16_t*   hbuf1 = (bf16_t*)(ws + 16384 + 131072);         // 128 KB
  bf16_t*   Wtf   = (bf16_t*)(ws + 16384 + 262144);         // 1 MB
  bf16_t*   xbf   = (bf16_t*)(ws + 16384 + 262144 + 1048576);  // 64 MB (optional)
  const size_t need_xbf = 16384 + 262144 + 1048576 + (size_t)BB * TT * XSZ * 2;

  hipMemsetAsync(flags, 0, 8192, stream);

  prep_bias<<<dim3(4), dim3(256), 0, stream>>>(bx[0], bh[0], bx[1], bh[1],
                                               bx[2], bh[2], bx[3], bh[3], bias);
  prep_wtf<<<dim3(256), dim3(256), 0, stream>>>(wx[0], wh[0], wx[1], wh[1],
                                                wx[2], wh[2], wx[3], wh[3], Wtf);
  if (ws_size >= need_xbf) {
    prep_xbf<<<dim3((BB * TT * XSZ / 8) / 256), dim3(256), 0, stream>>>(x, xbf);
    lstm_seq<true><<<dim3(128), dim3(512), 0, stream>>>(xbf, Wtf, bias, hbuf0, hbuf1,
                                                        flags, (float*)d_out);
  } else {
    lstm_seq<false><<<dim3(128), dim3(512), 0, stream>>>(x, Wtf, bias, hbuf0, hbuf1,
                                                         flags, (float*)d_out);
  }
}

// Round 5
// 1861.176 us; speedup vs baseline: 6.5818x; 1.1708x over previous
//
#include <hip/hip_runtime.h>
#include <hip/hip_bf16.h>

#define BB   256   // batch
#define TT   512   // time steps
#define XSZ  256   // input size
#define HSZ  256   // hidden size
#define GLDSW 132  // gate LDS row stride (f32), 16 rows

typedef __bf16 bf16_t;
typedef __attribute__((ext_vector_type(8))) __bf16 bf16x8;
typedef __attribute__((ext_vector_type(4))) float  f32x4;
typedef __attribute__((ext_vector_type(4))) unsigned uint4v;

__device__ __forceinline__ float sigmoidf_(float v) { return 1.0f / (1.0f + __expf(-v)); }
__device__ __forceinline__ float tanhf_(float v)    { return 1.0f - 2.0f / (1.0f + __expf(2.0f * v)); }

// ---------------- prep: bias[g*256+c] = bx_g[c] + bh_g[c] ----------------
__global__ void prep_bias(const float* bx0, const float* bh0, const float* bx1, const float* bh1,
                          const float* bx2, const float* bh2, const float* bx3, const float* bh3,
                          float* bias) {
  const float* bxs[4] = {bx0, bx1, bx2, bx3};
  const float* bhs[4] = {bh0, bh1, bh2, bh3};
  int g = blockIdx.x, c = threadIdx.x;
  bias[g * 256 + c] = bxs[g][c] + bhs[g][c];
}

// ---------------- prep: fragment-linear weight pack (round-4 layout) ----------------
__global__ void prep_wtf(const float* wx0, const float* wh0, const float* wx1, const float* wh1,
                         const float* wx2, const float* wh2, const float* wx3, const float* wh3,
                         bf16_t* Wtf) {
  const float* whs[4] = {wh0, wh1, wh2, wh3};
  const float* wxs[4] = {wx0, wx1, wx2, wx3};
  int id = blockIdx.x * 256 + threadIdx.x;    // 65536 = 1024 chunks x 64 lanes
  int L  = id & 63;
  int kt = (id >> 6) & 15;
  int w  = (id >> 10) & 7;
  int j  = (id >> 13) & 7;
  int sec = w >> 1, half = w & 1;
  int c   = j * 32 + half * 16 + (L & 15);    // hidden col 0..255
  int k0  = kt * 32 + (L >> 4) * 8;
  const float* src = (k0 < 256) ? (whs[sec] + (size_t)k0 * 256 + c)
                                : (wxs[sec] + (size_t)(k0 - 256) * 256 + c);
  bf16x8 v;
#pragma unroll
  for (int i = 0; i < 8; ++i) v[i] = (__bf16)src[(size_t)i * 256];
  reinterpret_cast<bf16x8*>(Wtf)[id] = v;
}

// ---------------- prep: x f32 -> bf16 ----------------
__global__ void prep_xbf(const float* __restrict__ x, bf16_t* __restrict__ xb) {
  size_t id = (size_t)blockIdx.x * 256 + threadIdx.x;   // x8 elements
  const float* p = x + id * 8;
  f32x4 lo = *reinterpret_cast<const f32x4*>(p);
  f32x4 hi = *reinterpret_cast<const f32x4*>(p + 4);
  bf16x8 v;
#pragma unroll
  for (int i = 0; i < 4; ++i) { v[i] = (__bf16)lo[i]; v[i + 4] = (__bf16)hi[i]; }
  reinterpret_cast<bf16x8*>(xb)[id] = v;
}

// ---------------- main sequential LSTM ----------------
// 128 blocks = 16 groups x 8 column-blocks. h exchanged through MALL as
// self-validating dwords {seq16 = t, h bf16} — ONE load round trip per step,
// no flags, no store-ack. Parity double-buffer over t&1. x-loads for t+1
// issued before the poll so their latency hides under the exchange.
template <bool XBF>
__global__ __launch_bounds__(512, 2)
void lstm_seq(const void* __restrict__ xsrc, const bf16_t* __restrict__ Wtf,
              const float* __restrict__ bias, unsigned* __restrict__ hseq,
              float* __restrict__ out)
{
  __shared__ __align__(16) char  bxlds[65536];     // Wx slice, fragment-linear
  __shared__ __align__(16) char  hxl[2][8192];     // h A-frags, double-buffered
  __shared__ __align__(16) float glds[16 * GLDSW]; // gate tile 16 x 128 (+pad)

  const int tid  = threadIdx.x;
  const int w    = tid >> 6;
  const int lane = tid & 63;
  const int l15  = lane & 15, l4 = lane >> 4;
  const int bid  = blockIdx.x;
  const int g    = bid >> 3, j = bid & 7;
  const int b0   = g * 16;
  const int sec  = w >> 1, half = w & 1;
  const int C    = sec * 256 + j * 32 + half * 16 + l15;   // this lane's gate col

  const float*  xf32 = (const float*)xsrc;
  const bf16_t* xbf  = (const bf16_t*)xsrc;

  const float bias_v = bias[C];

  // ---- setup: Bh (kt 0..7) -> VGPRs; Bx (kt 8..15) -> LDS (wave-private)
  const char* wbase = (const char*)Wtf + ((size_t)(j * 8 + w) * 16) * 1024 + lane * 16;
  bf16x8 Bh[8];
#pragma unroll
  for (int kt = 0; kt < 8; ++kt)
    Bh[kt] = *reinterpret_cast<const bf16x8*>(wbase + kt * 1024);
#pragma unroll
  for (int q = 0; q < 8; ++q) {
    bf16x8 v = *reinterpret_cast<const bf16x8*>(wbase + (8 + q) * 1024);
    *reinterpret_cast<bf16x8*>(bxlds + (w * 8 + q) * 1024 + lane * 16) = v;
  }
  __syncthreads();

  // combine ownership: one cell per thread
  const int crow = tid >> 5;          // 0..15 (block row)
  const int ccol = tid & 31;          // 0..31 (hidden col local)
  float cst = 0.f;

  // ---- prologue: acc_x = bias + x_0 @ Wx
  f32x4 acc_x = {bias_v, bias_v, bias_v, bias_v};
#pragma unroll
  for (int k8 = 0; k8 < 8; ++k8) {
    bf16x8 a;
    if constexpr (XBF) {
      a = *reinterpret_cast<const bf16x8*>(
          xbf + (size_t)(b0 + l15) * (TT * XSZ) + k8 * 32 + l4 * 8);
    } else {
      const float* xp = xf32 + (size_t)(b0 + l15) * (TT * XSZ) + k8 * 32 + l4 * 8;
      f32x4 lo = *reinterpret_cast<const f32x4*>(xp);
      f32x4 hi = *reinterpret_cast<const f32x4*>(xp + 4);
#pragma unroll
      for (int i = 0; i < 4; ++i) { a[i] = (__bf16)lo[i]; a[i + 4] = (__bf16)hi[i]; }
    }
    bf16x8 bx = *reinterpret_cast<const bf16x8*>(bxlds + (w * 8 + k8) * 1024 + lane * 16);
    acc_x = __builtin_amdgcn_mfma_f32_16x16x32_bf16(a, bx, acc_x, 0, 0, 0);
  }

#pragma unroll 1
  for (int t = 0; t < TT; ++t) {
    f32x4 acc = acc_x;

    // ---- early-issue x A-frag loads for t+1 (latency hides under exchange)
    bf16x8 ax[8];
    if constexpr (XBF) {
      if (t + 1 < TT) {
#pragma unroll
        for (int k8 = 0; k8 < 8; ++k8)
          ax[k8] = *reinterpret_cast<const bf16x8*>(
              xbf + (size_t)(b0 + l15) * (TT * XSZ) + (size_t)(t + 1) * XSZ + k8 * 32 + l4 * 8);
      }
    }

    if (t > 0) {
      // ---- ONE-round-trip exchange: load 8 self-validating h dwords
      const unsigned* hp = hseq + (size_t)(t & 1) * 65536
                         + (size_t)(b0 + l15) * HSZ + w * 32 + l4 * 8;
      const unsigned tg = (unsigned)t;
      uint4v A, B;
      for (;;) {
        asm volatile("global_load_dwordx4 %0, %2, off sc0 sc1\n\t"
                     "global_load_dwordx4 %1, %2, off offset:16 sc0 sc1\n\t"
                     "s_waitcnt vmcnt(0)"
                     : "=&v"(A), "=&v"(B) : "v"(hp) : "memory");
        bool ok = ((A[0] >> 16) == tg) & ((A[1] >> 16) == tg) &
                  ((A[2] >> 16) == tg) & ((A[3] >> 16) == tg) &
                  ((B[0] >> 16) == tg) & ((B[1] >> 16) == tg) &
                  ((B[2] >> 16) == tg) & ((B[3] >> 16) == tg);
        if (__all((int)ok)) break;
        __builtin_amdgcn_s_sleep(1);
      }
      __builtin_amdgcn_sched_barrier(0);
      // pack 8 lo16 -> bf16x8 A-frag, dedupe via LDS (wave w supplies kt=w)
      unsigned p0 = (A[0] & 0xFFFFu) | (A[1] << 16);
      unsigned p1 = (A[2] & 0xFFFFu) | (A[3] << 16);
      unsigned p2 = (B[0] & 0xFFFFu) | (B[1] << 16);
      unsigned p3 = (B[2] & 0xFFFFu) | (B[3] << 16);
      uint4v pk = {p0, p1, p2, p3};
      *reinterpret_cast<uint4v*>(hxl[t & 1] + w * 1024 + lane * 16) = pk;
    }
    __syncthreads();   // hxl[t&1] complete (t=0: plain sync)

    if (t > 0) {
      // ---- critical MFMAs: acc += h(t) @ Wh (B from VGPRs)
#pragma unroll
      for (int kt = 0; kt < 8; ++kt) {
        bf16x8 a = *reinterpret_cast<const bf16x8*>(hxl[t & 1] + kt * 1024 + lane * 16);
        acc = __builtin_amdgcn_mfma_f32_16x16x32_bf16(a, Bh[kt], acc, 0, 0, 0);
      }
    }

    // ---- gates -> LDS (C-frag: row l4*4+r, col_local sec*32 + half*16 + l15)
    {
      const int col = sec * 32 + half * 16 + l15;
#pragma unroll
      for (int r = 0; r < 4; ++r)
        glds[(l4 * 4 + r) * GLDSW + col] = acc[r];
    }
    __syncthreads();

    // ---- combine: thread owns (crow, ccol)
    const float* gp = &glds[crow * GLDSW + ccol];
    float i_t = sigmoidf_(gp[0]);
    float f_t = sigmoidf_(gp[32]);
    float g_t = tanhf_(gp[64]);
    float o_t = sigmoidf_(gp[96]);
    float cn  = f_t * cst + i_t * g_t;
    cst = cn;
    float hval = o_t * tanhf_(cn);

    if (t + 1 < TT) {
      // ---- publish h(t+1) as {seq16, bf16} — fire-and-forget, self-validating
      __bf16 hb16 = (__bf16)hval;
      unsigned hv = ((unsigned)(t + 1) << 16)
                  | (unsigned)__builtin_bit_cast(unsigned short, hb16);
      unsigned* hp = hseq + (size_t)((t + 1) & 1) * 65536
                   + (size_t)(b0 + crow) * HSZ + j * 32 + ccol;
      asm volatile("global_store_dword %0, %1, off sc0 sc1" :: "v"(hp), "v"(hv) : "memory");

      // ---- acc_x = bias + x_{t+1} @ Wx (x already in regs for XBF)
      acc_x = f32x4{bias_v, bias_v, bias_v, bias_v};
#pragma unroll
      for (int k8 = 0; k8 < 8; ++k8) {
        bf16x8 a;
        if constexpr (XBF) {
          a = ax[k8];
        } else {
          const float* xp = xf32 + (size_t)(b0 + l15) * (TT * XSZ)
                          + (size_t)(t + 1) * XSZ + k8 * 32 + l4 * 8;
          f32x4 lo = *reinterpret_cast<const f32x4*>(xp);
          f32x4 hi = *reinterpret_cast<const f32x4*>(xp + 4);
#pragma unroll
          for (int i = 0; i < 4; ++i) { a[i] = (__bf16)lo[i]; a[i + 4] = (__bf16)hi[i]; }
        }
        bf16x8 bx = *reinterpret_cast<const bf16x8*>(bxlds + (w * 8 + k8) * 1024 + lane * 16);
        acc_x = __builtin_amdgcn_mfma_f32_16x16x32_bf16(a, bx, acc_x, 0, 0, 0);
      }
    } else {
      float* op = out + (size_t)(b0 + crow) * HSZ + j * 32 + ccol;
      op[0] = hval;
      op[(size_t)BB * HSZ] = cst;
    }
    // glds reads done; next iteration's writes are gated by the next barrier
  }
}

extern "C" void kernel_launch(void* const* d_in, const int* in_sizes, int n_in,
                              void* d_out, int out_size, void* d_ws, size_t ws_size,
                              hipStream_t stream) {
  const float* x = (const float*)d_in[0];
  const float *wx[4], *wh[4], *bx[4], *bh[4];
  for (int g = 0; g < 4; ++g) {          // dict order: wx, wh, bx, bh per gate (i,f,g,o)
    wx[g] = (const float*)d_in[1 + 4 * g];
    wh[g] = (const float*)d_in[2 + 4 * g];
    bx[g] = (const float*)d_in[3 + 4 * g];
    bh[g] = (const float*)d_in[4 + 4 * g];
  }

  char* ws = (char*)d_ws;
  float*    bias = (float*)ws;                                   // 4 KB
  bf16_t*   Wtf  = (bf16_t*)(ws + 4096);                         // 1 MB
  unsigned* hseq = (unsigned*)(ws + 4096 + 1048576);             // 512 KB (2 x 64K dwords)
  bf16_t*   xbf  = (bf16_t*)(ws + 4096 + 1048576 + 524288);      // 64 MB (optional)
  const size_t need_xbf = 4096 + 1048576 + 524288 + (size_t)BB * TT * XSZ * 2;

  prep_bias<<<dim3(4), dim3(256), 0, stream>>>(bx[0], bh[0], bx[1], bh[1],
                                               bx[2], bh[2], bx[3], bh[3], bias);
  prep_wtf<<<dim3(256), dim3(256), 0, stream>>>(wx[0], wh[0], wx[1], wh[1],
                                                wx[2], wh[2], wx[3], wh[3], Wtf);
  if (ws_size >= need_xbf) {
    prep_xbf<<<dim3((BB * TT * XSZ / 8) / 256), dim3(256), 0, stream>>>(x, xbf);
    lstm_seq<true><<<dim3(128), dim3(512), 0, stream>>>(xbf, Wtf, bias, hseq,
                                                        (float*)d_out);
  } else {
    lstm_seq<false><<<dim3(128), dim3(512), 0, stream>>>(x, Wtf, bias, hseq,
                                                         (float*)d_out);
  }
}

// Round 6
// 1860.541 us; speedup vs baseline: 6.5841x; 1.0003x over previous
//
#include <hip/hip_runtime.h>
#include <hip/hip_bf16.h>

#define BB   256   // batch
#define TT   512   // time steps
#define XSZ  256   // input size
#define HSZ  256   // hidden size
#define GLDSW 132  // gate LDS row stride (f32), 16 rows

typedef __bf16 bf16_t;
typedef __attribute__((ext_vector_type(8))) __bf16 bf16x8;
typedef __attribute__((ext_vector_type(4))) float  f32x4;
typedef __attribute__((ext_vector_type(4))) unsigned uint4v;

__device__ __forceinline__ float sigmoidf_(float v) { return 1.0f / (1.0f + __expf(-v)); }
__device__ __forceinline__ float tanhf_(float v)    { return 1.0f - 2.0f / (1.0f + __expf(2.0f * v)); }

// ---------------- prep: bias[g*256+c] = bx_g[c] + bh_g[c] ----------------
__global__ void prep_bias(const float* bx0, const float* bh0, const float* bx1, const float* bh1,
                          const float* bx2, const float* bh2, const float* bx3, const float* bh3,
                          float* bias) {
  const float* bxs[4] = {bx0, bx1, bx2, bx3};
  const float* bhs[4] = {bh0, bh1, bh2, bh3};
  int g = blockIdx.x, c = threadIdx.x;
  bias[g * 256 + c] = bxs[g][c] + bhs[g][c];
}

// ---------------- prep: fragment-linear weight pack (round-4 layout) ----------------
__global__ void prep_wtf(const float* wx0, const float* wh0, const float* wx1, const float* wh1,
                         const float* wx2, const float* wh2, const float* wx3, const float* wh3,
                         bf16_t* Wtf) {
  const float* whs[4] = {wh0, wh1, wh2, wh3};
  const float* wxs[4] = {wx0, wx1, wx2, wx3};
  int id = blockIdx.x * 256 + threadIdx.x;    // 65536 = 1024 chunks x 64 lanes
  int L  = id & 63;
  int kt = (id >> 6) & 15;
  int w  = (id >> 10) & 7;
  int j  = (id >> 13) & 7;
  int sec = w >> 1, half = w & 1;
  int c   = j * 32 + half * 16 + (L & 15);    // hidden col 0..255
  int k0  = kt * 32 + (L >> 4) * 8;
  const float* src = (k0 < 256) ? (whs[sec] + (size_t)k0 * 256 + c)
                                : (wxs[sec] + (size_t)(k0 - 256) * 256 + c);
  bf16x8 v;
#pragma unroll
  for (int i = 0; i < 8; ++i) v[i] = (__bf16)src[(size_t)i * 256];
  reinterpret_cast<bf16x8*>(Wtf)[id] = v;
}

// ---------------- prep: x f32 -> bf16 ----------------
__global__ void prep_xbf(const float* __restrict__ x, bf16_t* __restrict__ xb) {
  size_t id = (size_t)blockIdx.x * 256 + threadIdx.x;   // x8 elements
  const float* p = x + id * 8;
  f32x4 lo = *reinterpret_cast<const f32x4*>(p);
  f32x4 hi = *reinterpret_cast<const f32x4*>(p + 4);
  bf16x8 v;
#pragma unroll
  for (int i = 0; i < 4; ++i) { v[i] = (__bf16)lo[i]; v[i + 4] = (__bf16)hi[i]; }
  reinterpret_cast<bf16x8*>(xb)[id] = v;
}

// ---------------- main sequential LSTM ----------------
// 128 blocks = 16 groups x 8 column-blocks. h exchanged through MALL as
// self-validating dwords {seq16 = t, h bf16} — ONE load round trip per step,
// no flags, no store-ack. Parity double-buffer over t&1. x-loads for t+1
// issued before the poll so their latency hides under the exchange.
template <bool XBF>
__global__ __launch_bounds__(512, 2)
void lstm_seq(const void* __restrict__ xsrc, const bf16_t* __restrict__ Wtf,
              const float* __restrict__ bias, unsigned* __restrict__ hseq,
              float* __restrict__ out)
{
  __shared__ __align__(16) char  bxlds[65536];     // Wx slice, fragment-linear
  __shared__ __align__(16) char  hxl[2][8192];     // h A-frags, double-buffered
  __shared__ __align__(16) float glds[16 * GLDSW]; // gate tile 16 x 128 (+pad)

  const int tid  = threadIdx.x;
  const int w    = tid >> 6;
  const int lane = tid & 63;
  const int l15  = lane & 15, l4 = lane >> 4;
  const int bid  = blockIdx.x;
  const int g    = bid >> 3, j = bid & 7;
  const int b0   = g * 16;
  const int sec  = w >> 1, half = w & 1;
  const int C    = sec * 256 + j * 32 + half * 16 + l15;   // this lane's gate col

  const float*  xf32 = (const float*)xsrc;
  const bf16_t* xbf  = (const bf16_t*)xsrc;

  const float bias_v = bias[C];

  // ---- setup: Bh (kt 0..7) -> VGPRs; Bx (kt 8..15) -> LDS (wave-private)
  const char* wbase = (const char*)Wtf + ((size_t)(j * 8 + w) * 16) * 1024 + lane * 16;
  bf16x8 Bh[8];
#pragma unroll
  for (int kt = 0; kt < 8; ++kt)
    Bh[kt] = *reinterpret_cast<const bf16x8*>(wbase + kt * 1024);
#pragma unroll
  for (int q = 0; q < 8; ++q) {
    bf16x8 v = *reinterpret_cast<const bf16x8*>(wbase + (8 + q) * 1024);
    *reinterpret_cast<bf16x8*>(bxlds + (w * 8 + q) * 1024 + lane * 16) = v;
  }
  __syncthreads();

  // combine ownership: one cell per thread
  const int crow = tid >> 5;          // 0..15 (block row)
  const int ccol = tid & 31;          // 0..31 (hidden col local)
  float cst = 0.f;

  // ---- prologue: acc_x = bias + x_0 @ Wx
  f32x4 acc_x = {bias_v, bias_v, bias_v, bias_v};
#pragma unroll
  for (int k8 = 0; k8 < 8; ++k8) {
    bf16x8 a;
    if constexpr (XBF) {
      a = *reinterpret_cast<const bf16x8*>(
          xbf + (size_t)(b0 + l15) * (TT * XSZ) + k8 * 32 + l4 * 8);
    } else {
      const float* xp = xf32 + (size_t)(b0 + l15) * (TT * XSZ) + k8 * 32 + l4 * 8;
      f32x4 lo = *reinterpret_cast<const f32x4*>(xp);
      f32x4 hi = *reinterpret_cast<const f32x4*>(xp + 4);
#pragma unroll
      for (int i = 0; i < 4; ++i) { a[i] = (__bf16)lo[i]; a[i + 4] = (__bf16)hi[i]; }
    }
    bf16x8 bx = *reinterpret_cast<const bf16x8*>(bxlds + (w * 8 + k8) * 1024 + lane * 16);
    acc_x = __builtin_amdgcn_mfma_f32_16x16x32_bf16(a, bx, acc_x, 0, 0, 0);
  }

#pragma unroll 1
  for (int t = 0; t < TT; ++t) {
    f32x4 acc = acc_x;

    // ---- early-issue x A-frag loads for t+1 (latency hides under exchange)
    bf16x8 ax[8];
    if constexpr (XBF) {
      if (t + 1 < TT) {
#pragma unroll
        for (int k8 = 0; k8 < 8; ++k8)
          ax[k8] = *reinterpret_cast<const bf16x8*>(
              xbf + (size_t)(b0 + l15) * (TT * XSZ) + (size_t)(t + 1) * XSZ + k8 * 32 + l4 * 8);
      }
    }

    if (t > 0) {
      // ---- ONE-round-trip exchange: load 8 self-validating h dwords
      const unsigned* hp = hseq + (size_t)(t & 1) * 65536
                         + (size_t)(b0 + l15) * HSZ + w * 32 + l4 * 8;
      const unsigned tg = (unsigned)t;
      uint4v A, B;
      for (;;) {
        asm volatile("global_load_dwordx4 %0, %2, off sc0 sc1\n\t"
                     "global_load_dwordx4 %1, %2, off offset:16 sc0 sc1\n\t"
                     "s_waitcnt vmcnt(0)"
                     : "=&v"(A), "=&v"(B) : "v"(hp) : "memory");
        bool ok = ((A[0] >> 16) == tg) & ((A[1] >> 16) == tg) &
                  ((A[2] >> 16) == tg) & ((A[3] >> 16) == tg) &
                  ((B[0] >> 16) == tg) & ((B[1] >> 16) == tg) &
                  ((B[2] >> 16) == tg) & ((B[3] >> 16) == tg);
        if (__all((int)ok)) break;
        __builtin_amdgcn_s_sleep(1);
      }
      __builtin_amdgcn_sched_barrier(0);
      // pack 8 lo16 -> bf16x8 A-frag, dedupe via LDS (wave w supplies kt=w)
      unsigned p0 = (A[0] & 0xFFFFu) | (A[1] << 16);
      unsigned p1 = (A[2] & 0xFFFFu) | (A[3] << 16);
      unsigned p2 = (B[0] & 0xFFFFu) | (B[1] << 16);
      unsigned p3 = (B[2] & 0xFFFFu) | (B[3] << 16);
      uint4v pk = {p0, p1, p2, p3};
      *reinterpret_cast<uint4v*>(hxl[t & 1] + w * 1024 + lane * 16) = pk;
    }
    __syncthreads();   // hxl[t&1] complete (t=0: plain sync)

    if (t > 0) {
      // ---- critical MFMAs: acc += h(t) @ Wh (B from VGPRs)
#pragma unroll
      for (int kt = 0; kt < 8; ++kt) {
        bf16x8 a = *reinterpret_cast<const bf16x8*>(hxl[t & 1] + kt * 1024 + lane * 16);
        acc = __builtin_amdgcn_mfma_f32_16x16x32_bf16(a, Bh[kt], acc, 0, 0, 0);
      }
    }

    // ---- gates -> LDS (C-frag: row l4*4+r, col_local sec*32 + half*16 + l15)
    {
      const int col = sec * 32 + half * 16 + l15;
#pragma unroll
      for (int r = 0; r < 4; ++r)
        glds[(l4 * 4 + r) * GLDSW + col] = acc[r];
    }
    __syncthreads();

    // ---- combine: thread owns (crow, ccol)
    const float* gp = &glds[crow * GLDSW + ccol];
    float i_t = sigmoidf_(gp[0]);
    float f_t = sigmoidf_(gp[32]);
    float g_t = tanhf_(gp[64]);
    float o_t = sigmoidf_(gp[96]);
    float cn  = f_t * cst + i_t * g_t;
    cst = cn;
    float hval = o_t * tanhf_(cn);

    if (t + 1 < TT) {
      // ---- publish h(t+1) as {seq16, bf16} — fire-and-forget, self-validating
      __bf16 hb16 = (__bf16)hval;
      unsigned hv = ((unsigned)(t + 1) << 16)
                  | (unsigned)__builtin_bit_cast(unsigned short, hb16);
      unsigned* hp = hseq + (size_t)((t + 1) & 1) * 65536
                   + (size_t)(b0 + crow) * HSZ + j * 32 + ccol;
      asm volatile("global_store_dword %0, %1, off sc0 sc1" :: "v"(hp), "v"(hv) : "memory");

      // ---- acc_x = bias + x_{t+1} @ Wx (x already in regs for XBF)
      acc_x = f32x4{bias_v, bias_v, bias_v, bias_v};
#pragma unroll
      for (int k8 = 0; k8 < 8; ++k8) {
        bf16x8 a;
        if constexpr (XBF) {
          a = ax[k8];
        } else {
          const float* xp = xf32 + (size_t)(b0 + l15) * (TT * XSZ)
                          + (size_t)(t + 1) * XSZ + k8 * 32 + l4 * 8;
          f32x4 lo = *reinterpret_cast<const f32x4*>(xp);
          f32x4 hi = *reinterpret_cast<const f32x4*>(xp + 4);
#pragma unroll
          for (int i = 0; i < 4; ++i) { a[i] = (__bf16)lo[i]; a[i + 4] = (__bf16)hi[i]; }
        }
        bf16x8 bx = *reinterpret_cast<const bf16x8*>(bxlds + (w * 8 + k8) * 1024 + lane * 16);
        acc_x = __builtin_amdgcn_mfma_f32_16x16x32_bf16(a, bx, acc_x, 0, 0, 0);
      }
    } else {
      float* op = out + (size_t)(b0 + crow) * HSZ + j * 32 + ccol;
      op[0] = hval;
      op[(size_t)BB * HSZ] = cst;
    }
    // glds reads done; next iteration's writes are gated by the next barrier
  }
}

extern "C" void kernel_launch(void* const* d_in, const int* in_sizes, int n_in,
                              void* d_out, int out_size, void* d_ws, size_t ws_size,
                              hipStream_t stream) {
  const float* x = (const float*)d_in[0];
  const float *wx[4], *wh[4], *bx[4], *bh[4];
  for (int g = 0; g < 4; ++g) {          // dict order: wx, wh, bx, bh per gate (i,f,g,o)
    wx[g] = (const float*)d_in[1 + 4 * g];
    wh[g] = (const float*)d_in[2 + 4 * g];
    bx[g] = (const float*)d_in[3 + 4 * g];
    bh[g] = (const float*)d_in[4 + 4 * g];
  }

  char* ws = (char*)d_ws;
  float*    bias = (float*)ws;                                   // 4 KB
  bf16_t*   Wtf  = (bf16_t*)(ws + 4096);                         // 1 MB
  unsigned* hseq = (unsigned*)(ws + 4096 + 1048576);             // 512 KB (2 x 64K dwords)
  bf16_t*   xbf  = (bf16_t*)(ws + 4096 + 1048576 + 524288);      // 64 MB (optional)
  const size_t need_xbf = 4096 + 1048576 + 524288 + (size_t)BB * TT * XSZ * 2;

  prep_bias<<<dim3(4), dim3(256), 0, stream>>>(bx[0], bh[0], bx[1], bh[1],
                                               bx[2], bh[2], bx[3], bh[3], bias);
  prep_wtf<<<dim3(256), dim3(256), 0, stream>>>(wx[0], wh[0], wx[1], wh[1],
                                                wx[2], wh[2], wx[3], wh[3], Wtf);
  if (ws_size >= need_xbf) {
    prep_xbf<<<dim3((BB * TT * XSZ / 8) / 256), dim3(256), 0, stream>>>(x, xbf);
    lstm_seq<true><<<dim3(128), dim3(512), 0, stream>>>(xbf, Wtf, bias, hseq,
                                                        (float*)d_out);
  } else {
    lstm_seq<false><<<dim3(128), dim3(512), 0, stream>>>(x, Wtf, bias, hseq,
                                                         (float*)d_out);
  }
}